// Round 1
// baseline (658.613 us; speedup 1.0000x reference)
//
#include <hip/hip_runtime.h>
#include <hip/hip_cooperative_groups.h>
#include <stdint.h>

namespace cg = cooperative_groups;

// Problem constants (fixed by setup_inputs)
#define BATCH 64
#define NPTS  131072
#define MPTS  2048
#define WORDS_PB (NPTS / 64)       // 2048 mask words per batch
#define GRID_BLOCKS 1024           // 4 per CU; co-resident for cooperative launch
#define SPAN  8192                 // contiguous points per block (8192*16 = NPTS per batch, 16 blocks/batch)
#define P1_ITERS (SPAN / 1024)     // 8: 4 points per thread per iteration

// ---------------- Threefry-2x32-20, exactly as jax/_src/prng.py ----------------
struct U2 { uint32_t a, b; };

__host__ __device__ constexpr U2 tf2x32(uint32_t k0, uint32_t k1, uint32_t x0, uint32_t x1) {
  uint32_t ks0 = k0, ks1 = k1, ks2 = k0 ^ k1 ^ 0x1BD11BDAu;
  x0 += ks0; x1 += ks1;
  const int rotA[4] = {13, 15, 26, 6};
  const int rotB[4] = {17, 29, 16, 24};
  for (int r = 0; r < 4; ++r) { x0 += x1; x1 = (x1 << rotA[r]) | (x1 >> (32 - rotA[r])); x1 ^= x0; }
  x0 += ks1; x1 += ks2 + 1u;
  for (int r = 0; r < 4; ++r) { x0 += x1; x1 = (x1 << rotB[r]) | (x1 >> (32 - rotB[r])); x1 ^= x0; }
  x0 += ks2; x1 += ks0 + 2u;
  for (int r = 0; r < 4; ++r) { x0 += x1; x1 = (x1 << rotA[r]) | (x1 >> (32 - rotA[r])); x1 ^= x0; }
  x0 += ks0; x1 += ks1 + 3u;
  for (int r = 0; r < 4; ++r) { x0 += x1; x1 = (x1 << rotB[r]) | (x1 >> (32 - rotB[r])); x1 ^= x0; }
  x0 += ks1; x1 += ks2 + 4u;
  for (int r = 0; r < 4; ++r) { x0 += x1; x1 = (x1 << rotA[r]) | (x1 >> (32 - rotA[r])); x1 ^= x0; }
  x0 += ks2; x1 += ks0 + 5u;
  return U2{x0, x1};
}

// Spread 16 bits of x so bit i lands at bit 4*i of the result.
__device__ __forceinline__ unsigned long long spread4(unsigned long long x) {
  x &= 0xFFFFull;
  x = (x | (x << 24)) & 0x000000FF000000FFull;
  x = (x | (x << 12)) & 0x000F000F000F000Full;
  x = (x | (x << 6))  & 0x0303030303030303ull;
  x = (x | (x << 3))  & 0x1111111111111111ull;
  return x;
}

// ---------------- Single fused cooperative kernel ----------------
// Phase 1: streaming mask build + per-block partial xyz sums (wide loads, 4 pts/lane/iter)
// grid.sync
// Phase 2: blocks 0..63 — word-level exclusive prefix + count + mean
// grid.sync
// Phase 3: blocks 0..511 — threefry randint + rank-select + centered gather
__global__ __launch_bounds__(256, 4) void fused_kernel(
    const float4* __restrict__ pc, const float* __restrict__ lg,
    float* __restrict__ out, float* __restrict__ sumsPartial,
    int* __restrict__ cnt, float* __restrict__ mean,
    uint32_t* __restrict__ wordOff, unsigned long long* __restrict__ maskWords) {
  cg::grid_group grid = cg::this_grid();
  const int g = blockIdx.x;
  const int t = threadIdx.x;
  const int lane = t & 63, wv = t >> 6;

  __shared__ uint32_t sOff[WORDS_PB];      // 8 KiB, used in phase 3

  // ---------------- Phase 1 ----------------
  {
    const int b = g >> 4;                          // 16 blocks per batch
    const size_t base = (size_t)g * SPAN;          // global point index base
    const size_t inb = base & (NPTS - 1);          // in-batch offset
    const float4* l0v = (const float4*)(lg + (size_t)b * (2 * NPTS) + inb);
    const float4* l1v = (const float4*)(lg + (size_t)b * (2 * NPTS) + NPTS + inb);
    const float4* pcg = pc + base;

    float sx = 0.f, sy = 0.f, sz = 0.f;
#pragma unroll 2
    for (int k = 0; k < P1_ITERS; ++k) {
      const int i = k * 256 + t;                   // float4 index within span/4
      float4 a0 = l0v[i];
      float4 a1 = l1v[i];
      float4 p0 = pcg[4 * i + 0];
      float4 p1 = pcg[4 * i + 1];
      float4 p2 = pcg[4 * i + 2];
      float4 p3 = pcg[4 * i + 3];
      bool m0 = a0.x < a1.x, m1 = a0.y < a1.y, m2 = a0.z < a1.z, m3 = a0.w < a1.w;
      unsigned long long B0 = __ballot(m0);
      unsigned long long B1 = __ballot(m1);
      unsigned long long B2 = __ballot(m2);
      unsigned long long B3 = __ballot(m3);
      // Wave covers 256 consecutive points at (base + k*1024 + wv*256).
      // Lane 16w+i's bit j belongs to word w at bit 4i+j — rebuild exact order
      // via 16->64 bit spread of each ballot's 16-bit slice.
      if ((lane & 15) == 0) {
        const int w = lane >> 4;
        const int sh = 16 * w;
        unsigned long long word = spread4((B0 >> sh) & 0xFFFFull)
                                | (spread4((B1 >> sh) & 0xFFFFull) << 1)
                                | (spread4((B2 >> sh) & 0xFFFFull) << 2)
                                | (spread4((B3 >> sh) & 0xFFFFull) << 3);
        maskWords[(base + (size_t)k * 1024 + (size_t)wv * 256 + (size_t)w * 64) >> 6] = word;
      }
      if (m0) { sx += p0.x; sy += p0.y; sz += p0.z; }
      if (m1) { sx += p1.x; sy += p1.y; sz += p1.z; }
      if (m2) { sx += p2.x; sy += p2.y; sz += p2.z; }
      if (m3) { sx += p3.x; sy += p3.y; sz += p3.z; }
    }

    for (int o = 32; o; o >>= 1) {
      sx += __shfl_down(sx, o, 64);
      sy += __shfl_down(sy, o, 64);
      sz += __shfl_down(sz, o, 64);
    }
    __shared__ float ssx[4], ssy[4], ssz[4];
    if (lane == 0) { ssx[wv] = sx; ssy[wv] = sy; ssz[wv] = sz; }
    __syncthreads();
    if (t == 0) {
      sumsPartial[g * 3 + 0] = ssx[0] + ssx[1] + ssx[2] + ssx[3];
      sumsPartial[g * 3 + 1] = ssy[0] + ssy[1] + ssy[2] + ssy[3];
      sumsPartial[g * 3 + 2] = ssz[0] + ssz[1] + ssz[2] + ssz[3];
    }
  }

  __threadfence();
  grid.sync();

  // ---------------- Phase 2 ----------------
  if (g < BATCH) {
    const int b = g;
    const unsigned long long* mw = maskWords + (size_t)b * WORDS_PB;
    const int basew = t * 8;
    int p[8];
    int local = 0;
#pragma unroll
    for (int k = 0; k < 8; ++k) { p[k] = __popcll(mw[basew + k]); local += p[k]; }

    int x = local;
#pragma unroll
    for (int o = 1; o < 64; o <<= 1) {
      int y = __shfl_up(x, o, 64);
      if (lane >= o) x += y;
    }
    __shared__ int wsum[4];
    if (lane == 63) wsum[wv] = x;
    __syncthreads();
    int add = 0;
#pragma unroll
    for (int u = 0; u < 4; ++u) add += (u < wv) ? wsum[u] : 0;
    int run = add + x - local;
    uint32_t* wo = wordOff + (size_t)b * WORDS_PB;
#pragma unroll
    for (int k = 0; k < 8; ++k) { wo[basew + k] = (uint32_t)run; run += p[k]; }

    if (t == 0) {
      const int ct = wsum[0] + wsum[1] + wsum[2] + wsum[3];
      cnt[b] = ct;
      float sx = 0.f, sy = 0.f, sz = 0.f;
#pragma unroll
      for (int i = 0; i < 16; ++i) {
        sx += sumsPartial[(b * 16 + i) * 3 + 0];
        sy += sumsPartial[(b * 16 + i) * 3 + 1];
        sz += sumsPartial[(b * 16 + i) * 3 + 2];
      }
      const float d = fmaxf((float)ct, 1.0f);
      const float mx = sx / d, my = sy / d, mz = sz / d;
      mean[b * 3 + 0] = mx; mean[b * 3 + 1] = my; mean[b * 3 + 2] = mz;
      float* om = out + (size_t)BATCH * MPTS * 3 + (size_t)b * 3;
      om[0] = mx; om[1] = my; om[2] = mz;
    }
  }

  __threadfence();
  grid.sync();

  // ---------------- Phase 3 ----------------
  if (g < (BATCH * MPTS) / 256) {                  // 512 blocks, 8 per batch
    const int b = g >> 3;
    const int j = (g & 7) * 256 + t;
    const int gid = b * MPTS + j;

    const uint32_t* wo = wordOff + (size_t)b * WORDS_PB;
#pragma unroll
    for (int k = 0; k < 8; ++k) sOff[t + k * 256] = wo[t + k * 256];
    __shared__ float sMean[3];
    __shared__ int sCnt;
    if (t < 3)  sMean[t] = mean[b * 3 + t];
    if (t == 0) sCnt = cnt[b];
    __syncthreads();

    const int cb = sCnt;
    float ox, oy, oz;
    if (cb == 0) {
      ox = oy = oz = (float)b;                     // reference fills empty batches with batch id
    } else {
      // jax.random.randint(key(42),(B,M),0,max(cnt,1)) — partitionable threefry
      constexpr U2 K1 = tf2x32(0u, 42u, 0u, 0u);   // split(key)[0]
      constexpr U2 K2 = tf2x32(0u, 42u, 0u, 1u);   // split(key)[1]
      const uint32_t span = (uint32_t)cb;
      U2 h = tf2x32(K1.a, K1.b, 0u, (uint32_t)gid);
      U2 l = tf2x32(K2.a, K2.b, 0u, (uint32_t)gid);
      uint32_t hb = h.a ^ h.b;                     // higher_bits (32-bit fold)
      uint32_t lb = l.a ^ l.b;                     // lower_bits
      uint32_t mul = 65536u % span;
      mul = (mul * mul) % span;                    // uint32 wrap, exactly as lax
      uint32_t off = ((hb % span) * mul + (lb % span)) % span;
      int r = (j < cb && cb <= MPTS) ? j : (int)off;

      // binary search: largest w with sOff[w] <= r (sOff[0]==0)
      int lo = 0;
#pragma unroll
      for (int step = 1024; step; step >>= 1) {
        int nxt = lo + step;
        if (nxt < WORDS_PB && sOff[nxt] <= (uint32_t)r) lo = nxt;
      }
      int rem = r - (int)sOff[lo];
      unsigned long long w = maskWords[(size_t)b * WORDS_PB + lo];

      // branchless 64-bit rank-select of the rem-th set bit
      uint32_t cur = (uint32_t)w;
      int bitbase = 0;
      int c = __popc(cur);
      if (rem >= c) { rem -= c; cur = (uint32_t)(w >> 32); bitbase = 32; }
      c = __popc(cur & 0xFFFFu); if (rem >= c) { rem -= c; cur >>= 16; bitbase += 16; }
      c = __popc(cur & 0xFFu);   if (rem >= c) { rem -= c; cur >>= 8;  bitbase += 8;  }
      c = __popc(cur & 0xFu);    if (rem >= c) { rem -= c; cur >>= 4;  bitbase += 4;  }
      c = __popc(cur & 0x3u);    if (rem >= c) { rem -= c; cur >>= 2;  bitbase += 2;  }
      c = (int)(cur & 1u);       if (rem >= c) {           cur >>= 1;  bitbase += 1;  }
      const int idx = lo * 64 + bitbase;

      float4 p = pc[(size_t)b * NPTS + idx];
      ox = p.x - sMean[0]; oy = p.y - sMean[1]; oz = p.z - sMean[2];
    }
    float* o = out + (size_t)gid * 3;
    o[0] = ox; o[1] = oy; o[2] = oz;
  }
}

// ---------------- launch ----------------
extern "C" void kernel_launch(void* const* d_in, const int* in_sizes, int n_in,
                              void* d_out, int out_size, void* d_ws, size_t ws_size,
                              hipStream_t stream) {
  const float4* pc = (const float4*)d_in[0];   // (B, N, 4) float32
  const float*  lg = (const float*)d_in[1];    // (B, 2, N) float32
  float* out = (float*)d_out;                  // obj (B,M,3) then mean (B,3)

  char* w = (char*)d_ws;
  float*    sumsPartial = (float*)(w + 0);                 // 1024*3 floats = 12288 B
  int*      cnt         = (int*)(w + 12288);               // 64 ints
  float*    mean        = (float*)(w + 12544);             // 64*3 floats -> ends 13312
  uint32_t* wordOff     = (uint32_t*)(w + 13312);          // 64*2048 u32 = 512 KiB -> ends 537600
  unsigned long long* maskWords =
      (unsigned long long*)(w + 537600);                   // 64*2048 u64 = 1 MiB -> ends 1586176

  // No memset needed: sumsPartial is fully written in phase 1 before any read.
  void* args[] = {
    (void*)&pc, (void*)&lg, (void*)&out, (void*)&sumsPartial,
    (void*)&cnt, (void*)&mean, (void*)&wordOff, (void*)&maskWords
  };
  hipLaunchCooperativeKernel((void*)fused_kernel, dim3(GRID_BLOCKS), dim3(256),
                             args, 0, stream);
}

// Round 2
// 239.379 us; speedup vs baseline: 2.7513x; 2.7513x over previous
//
#include <hip/hip_runtime.h>
#include <stdint.h>

// Problem constants (fixed by setup_inputs)
#define BATCH 64
#define NPTS  131072
#define MPTS  2048
#define WORDS_PB (NPTS / 64)       // 2048 mask words per batch
#define P1_BLOCKS 2048             // 8 per CU; 32 blocks per batch
#define SPAN  4096                 // contiguous points per block (4096*32 = NPTS)
#define P1_ITERS (SPAN / 1024)     // 4 iterations of 4 points/thread

// ---------------- Threefry-2x32-20, exactly as jax/_src/prng.py ----------------
struct U2 { uint32_t a, b; };

__host__ __device__ constexpr U2 tf2x32(uint32_t k0, uint32_t k1, uint32_t x0, uint32_t x1) {
  uint32_t ks0 = k0, ks1 = k1, ks2 = k0 ^ k1 ^ 0x1BD11BDAu;
  x0 += ks0; x1 += ks1;
  const int rotA[4] = {13, 15, 26, 6};
  const int rotB[4] = {17, 29, 16, 24};
  for (int r = 0; r < 4; ++r) { x0 += x1; x1 = (x1 << rotA[r]) | (x1 >> (32 - rotA[r])); x1 ^= x0; }
  x0 += ks1; x1 += ks2 + 1u;
  for (int r = 0; r < 4; ++r) { x0 += x1; x1 = (x1 << rotB[r]) | (x1 >> (32 - rotB[r])); x1 ^= x0; }
  x0 += ks2; x1 += ks0 + 2u;
  for (int r = 0; r < 4; ++r) { x0 += x1; x1 = (x1 << rotA[r]) | (x1 >> (32 - rotA[r])); x1 ^= x0; }
  x0 += ks0; x1 += ks1 + 3u;
  for (int r = 0; r < 4; ++r) { x0 += x1; x1 = (x1 << rotB[r]) | (x1 >> (32 - rotB[r])); x1 ^= x0; }
  x0 += ks1; x1 += ks2 + 4u;
  for (int r = 0; r < 4; ++r) { x0 += x1; x1 = (x1 << rotA[r]) | (x1 >> (32 - rotA[r])); x1 ^= x0; }
  x0 += ks2; x1 += ks0 + 5u;
  return U2{x0, x1};
}

// ---------------- Pass 1: streaming mask + per-block partial xyz sums ----------------
// 2048 blocks (8/CU), each owns 4096 CONTIGUOUS points within one batch.
// Each thread processes 4 points per iteration at stride 256, so EVERY load
// instruction is contiguous across lanes (logits: 256 B/instr, pc: 1 KB/instr),
// and 12 independent loads per iteration (x2 unroll) keep ~6-12 KB/wave in
// flight — the old kernel's VGPR_Count=16 allowed only ~2 loads in flight,
// capping delivered BW at 2.4 TB/s.
__global__ __launch_bounds__(256, 4) void pass1_kernel(
    const float4* __restrict__ pc, const float* __restrict__ lg,
    float* __restrict__ sumsPartial, unsigned long long* __restrict__ maskWords) {
  const int g = blockIdx.x;
  const int t = threadIdx.x;
  const int lane = t & 63, wv = t >> 6;
  const int b = g >> 5;                         // 32 blocks per batch
  const size_t base = (size_t)g * SPAN;         // global point index base
  const size_t inb  = base & (NPTS - 1);        // in-batch offset
  const float*  l0g = lg + (size_t)b * (2 * NPTS) + inb;
  const float*  l1g = l0g + NPTS;
  const float4* pcg = pc + base;

  float sx = 0.f, sy = 0.f, sz = 0.f;
#pragma unroll 2
  for (int k = 0; k < P1_ITERS; ++k) {
    float a0q[4], a1q[4];
    float4 pq[4];
#pragma unroll
    for (int q = 0; q < 4; ++q) {
      const int idx = k * 1024 + q * 256 + t;
      a0q[q] = l0g[idx];
      a1q[q] = l1g[idx];
      pq[q]  = pcg[idx];
    }
#pragma unroll
    for (int q = 0; q < 4; ++q) {
      const bool m = a0q[q] < a1q[q];
      const unsigned long long bal = __ballot(m);
      if (lane == 0)
        maskWords[(base + (size_t)(k * 1024 + q * 256 + wv * 64)) >> 6] = bal;
      if (m) { sx += pq[q].x; sy += pq[q].y; sz += pq[q].z; }
    }
  }

  // wave (64-lane) reduce, then cross-wave via LDS
  for (int o = 32; o; o >>= 1) {
    sx += __shfl_down(sx, o, 64);
    sy += __shfl_down(sy, o, 64);
    sz += __shfl_down(sz, o, 64);
  }
  __shared__ float ssx[4], ssy[4], ssz[4];
  if (lane == 0) { ssx[wv] = sx; ssy[wv] = sy; ssz[wv] = sz; }
  __syncthreads();
  if (t == 0) {
    sumsPartial[g * 3 + 0] = ssx[0] + ssx[1] + ssx[2] + ssx[3];
    sumsPartial[g * 3 + 1] = ssy[0] + ssy[1] + ssy[2] + ssy[3];
    sumsPartial[g * 3 + 2] = ssz[0] + ssz[1] + ssz[2] + ssz[3];
  }
}

// ---------------- Pass 2 (fused scan + select + gather) ----------------
// 512 blocks, 8 per batch. Each block:
//   1. coalesced-loads its batch's 2048 mask words into LDS,
//   2. popcount + scan -> word-level exclusive prefix in LDS (was pass2),
//   3. wave 0 reduces the 32 per-block partial sums -> count/mean (was pass2),
//   4. threefry randint + binary-search + rank-select (word read from LDS) + gather.
__global__ __launch_bounds__(256) void pass3_kernel(
    const float4* __restrict__ pc, const float* __restrict__ sumsPartial,
    const unsigned long long* __restrict__ maskWords,
    float* __restrict__ out) {
  const int blk = blockIdx.x;
  const int b = blk >> 3;                       // 8 blocks per batch
  const int t = threadIdx.x;
  const int lane = t & 63, wv = t >> 6;
  const int j = (blk & 7) * 256 + t;
  const int gid = b * MPTS + j;

  __shared__ unsigned long long sW[WORDS_PB];   // 16 KiB: mask words for batch b
  __shared__ uint32_t sOff[WORDS_PB];           // 8 KiB: word-level exclusive prefix
  __shared__ int wsum[4];
  __shared__ float sMean[3];
  __shared__ int sCnt;

  const unsigned long long* mw = maskWords + (size_t)b * WORDS_PB;
#pragma unroll
  for (int k = 0; k < 8; ++k) sW[t + k * 256] = mw[t + k * 256];
  __syncthreads();

  // popcount + exclusive scan of the 2048 words (each thread owns 8 consecutive)
  const int basew = t * 8;
  int p[8];
  int local = 0;
#pragma unroll
  for (int k = 0; k < 8; ++k) { p[k] = __popcll(sW[basew + k]); local += p[k]; }

  int x = local;
#pragma unroll
  for (int o = 1; o < 64; o <<= 1) {
    const int y = __shfl_up(x, o, 64);
    if (lane >= o) x += y;
  }
  if (lane == 63) wsum[wv] = x;
  __syncthreads();
  int add = 0;
#pragma unroll
  for (int u = 0; u < 4; ++u) add += (u < wv) ? wsum[u] : 0;
  int run = add + x - local;
#pragma unroll
  for (int k = 0; k < 8; ++k) { sOff[basew + k] = (uint32_t)run; run += p[k]; }

  // wave 0: reduce the 32 per-block partial sums -> mean
  if (t < 64) {
    float px = 0.f, py = 0.f, pz = 0.f;
    if (t < 32) {
      const float* sp = sumsPartial + ((size_t)b * 32 + t) * 3;
      px = sp[0]; py = sp[1]; pz = sp[2];
    }
    for (int o = 32; o; o >>= 1) {
      px += __shfl_down(px, o, 64);
      py += __shfl_down(py, o, 64);
      pz += __shfl_down(pz, o, 64);
    }
    if (t == 0) {
      const int ct = wsum[0] + wsum[1] + wsum[2] + wsum[3];
      sCnt = ct;
      const float d = fmaxf((float)ct, 1.0f);
      sMean[0] = px / d; sMean[1] = py / d; sMean[2] = pz / d;
      if ((blk & 7) == 0) {
        float* om = out + (size_t)BATCH * MPTS * 3 + (size_t)b * 3;
        om[0] = sMean[0]; om[1] = sMean[1]; om[2] = sMean[2];
      }
    }
  }
  __syncthreads();

  const int cb = sCnt;
  float ox, oy, oz;
  if (cb == 0) {
    ox = oy = oz = (float)b;                    // reference fills empty batches with batch id
  } else {
    // jax.random.randint(key(42),(B,M),0,max(cnt,1)) — partitionable threefry
    constexpr U2 K1 = tf2x32(0u, 42u, 0u, 0u);  // split(key)[0]
    constexpr U2 K2 = tf2x32(0u, 42u, 0u, 1u);  // split(key)[1]
    const uint32_t span = (uint32_t)cb;
    U2 h = tf2x32(K1.a, K1.b, 0u, (uint32_t)gid);
    U2 l = tf2x32(K2.a, K2.b, 0u, (uint32_t)gid);
    uint32_t hb = h.a ^ h.b;                    // higher_bits (32-bit fold)
    uint32_t lb = l.a ^ l.b;                    // lower_bits
    uint32_t mul = 65536u % span;
    mul = (mul * mul) % span;                   // uint32 wrap, exactly as lax
    uint32_t off = ((hb % span) * mul + (lb % span)) % span;
    int r = (j < cb && cb <= MPTS) ? j : (int)off;

    // binary search: largest w with sOff[w] <= r (sOff[0]==0)
    int lo = 0;
#pragma unroll
    for (int step = 1024; step; step >>= 1) {
      const int nxt = lo + step;
      if (nxt < WORDS_PB && sOff[nxt] <= (uint32_t)r) lo = nxt;
    }
    int rem = r - (int)sOff[lo];
    const unsigned long long w = sW[lo];

    // branchless 64-bit rank-select of the rem-th set bit
    uint32_t cur = (uint32_t)w;
    int bitbase = 0;
    int c = __popc(cur);
    if (rem >= c) { rem -= c; cur = (uint32_t)(w >> 32); bitbase = 32; }
    c = __popc(cur & 0xFFFFu); if (rem >= c) { rem -= c; cur >>= 16; bitbase += 16; }
    c = __popc(cur & 0xFFu);   if (rem >= c) { rem -= c; cur >>= 8;  bitbase += 8;  }
    c = __popc(cur & 0xFu);    if (rem >= c) { rem -= c; cur >>= 4;  bitbase += 4;  }
    c = __popc(cur & 0x3u);    if (rem >= c) { rem -= c; cur >>= 2;  bitbase += 2;  }
    c = (int)(cur & 1u);       if (rem >= c) {           cur >>= 1;  bitbase += 1;  }
    const int idx = lo * 64 + bitbase;

    const float4 pnt = pc[(size_t)b * NPTS + idx];
    ox = pnt.x - sMean[0]; oy = pnt.y - sMean[1]; oz = pnt.z - sMean[2];
  }
  float* o = out + (size_t)gid * 3;
  o[0] = ox; o[1] = oy; o[2] = oz;
}

// ---------------- launch ----------------
extern "C" void kernel_launch(void* const* d_in, const int* in_sizes, int n_in,
                              void* d_out, int out_size, void* d_ws, size_t ws_size,
                              hipStream_t stream) {
  const float4* pc = (const float4*)d_in[0];   // (B, N, 4) float32
  const float*  lg = (const float*)d_in[1];    // (B, 2, N) float32
  float* out = (float*)d_out;                  // obj (B,M,3) then mean (B,3)

  char* w = (char*)d_ws;
  float* sumsPartial = (float*)(w + 0);                    // 2048*3 floats = 24576 B
  unsigned long long* maskWords =
      (unsigned long long*)(w + 24576);                    // 64*2048 u64 = 1 MiB

  // No memset: sumsPartial is fully written by pass1 before any read.
  pass1_kernel<<<P1_BLOCKS, 256, 0, stream>>>(pc, lg, sumsPartial, maskWords);
  pass3_kernel<<<(BATCH * MPTS) / 256, 256, 0, stream>>>(pc, sumsPartial, maskWords, out);
}